// Round 14
// baseline (569.005 us; speedup 1.0000x reference)
//
#include <hip/hip_runtime.h>

typedef unsigned short u16;
typedef __attribute__((ext_vector_type(8))) short s16x8;
typedef __attribute__((ext_vector_type(4))) float f32x4;

__device__ __forceinline__ u16 f2bf(float f) {
  unsigned u = __float_as_uint(f);
  u += 0x7fffu + ((u >> 16) & 1u);   // RNE
  return (u16)(u >> 16);
}
__device__ __forceinline__ float bf2f(u16 h) {
  return __uint_as_float(((unsigned)h) << 16);
}
__device__ __forceinline__ unsigned pk2(float lo, float hi) {
  return ((__float_as_uint(hi) + 0x8000u) & 0xffff0000u) |
         ((__float_as_uint(lo) + 0x8000u) >> 16);
}

typedef __attribute__((address_space(1))) const void gvoid_t;
typedef __attribute__((address_space(3))) void lvoid_t;
__device__ __forceinline__ void gload_lds16(const void* g, void* l) {
  __builtin_amdgcn_global_load_lds((gvoid_t*)g, (lvoid_t*)l, 16, 0, 0);
}

// ---------------- f32 -> bf16 convert (single region) ----------------
__global__ void cvt_f32_bf16(const float* __restrict__ in, u16* __restrict__ out, int n) {
  int i = (blockIdx.x * 256 + threadIdx.x) * 4;
  if (i >= n) return;
  float4 v = *(const float4*)(in + i);
  ushort4 o;
  o.x = f2bf(v.x); o.y = f2bf(v.y); o.z = f2bf(v.z); o.w = f2bf(v.w);
  *(ushort4*)(out + i) = o;
}

// ---------------- merged convert: X (2^23) + Wq/Wk/Wv (2^24 each) ----------------
__global__ void cvt4(const float* __restrict__ X,
                     const float* __restrict__ Wq, const float* __restrict__ Wk,
                     const float* __restrict__ Wv,
                     u16* __restrict__ Xb, u16* __restrict__ WB3) {
  long i = ((long)blockIdx.x * 256 + threadIdx.x) * 4;
  const float* src; u16* dst; long off;
  if (i < (1L << 23)) { src = X; dst = Xb; off = i; }
  else {
    long k = i - (1L << 23);
    int w = (int)(k >> 24);
    off = k & ((1L << 24) - 1);
    src = (w == 0) ? Wq : (w == 1) ? Wk : Wv;
    dst = WB3 + ((size_t)w << 24);
  }
  float4 v = *(const float4*)(src + off);
  ushort4 o;
  o.x = f2bf(v.x); o.y = f2bf(v.y); o.z = f2bf(v.z); o.w = f2bf(v.w);
  *(ushort4*)(dst + off) = o;
}

// ---------------- GEMM (R13 winner): out-proj ----------------
template<typename OutT, bool BIAS>
__global__ __launch_bounds__(256) void gemm_bt3(
    const u16* __restrict__ A, const u16* __restrict__ Bm,
    OutT* __restrict__ C, const float* __restrict__ bias,
    int M, int N, int K)
{
  __shared__ u16 As[3][128 * 32];
  __shared__ u16 Bs[3][128 * 32];

  const int t = threadIdx.x;
  const int lane = t & 63, wid = t >> 6;
  const int wm = wid >> 1, wn = wid & 1;
  const int lr = lane & 15, lk = lane >> 4;

  const int wg = blockIdx.x;
  const int xcd = wg & 7, j = wg >> 3;
  const int m0 = (j & 15) * 128;
  const int n0 = ((xcd << 2) | (j >> 4)) * 128;

  const int nt = K >> 5;

  f32x4 acc[4][4] = {};

#define STAGE3(KT)                                                             \
  {                                                                            \
    const int bu_ = (KT) % 3;                                                  \
    const int k0_ = (KT) << 5;                                                 \
    _Pragma("unroll")                                                          \
    for (int it = 0; it < 2; ++it) {                                           \
      int id = it * 256 + t;                                                   \
      int r = id >> 2, c0 = id & 3;                                            \
      int cs = (c0 ^ ((r >> 1) & 3)) << 3;                                     \
      gload_lds16(A + (size_t)(m0 + r) * K + k0_ + cs, &As[bu_][id * 8]);      \
      gload_lds16(Bm + (size_t)(n0 + r) * K + k0_ + cs, &Bs[bu_][id * 8]);     \
    }                                                                          \
  }

  STAGE3(0);
  STAGE3(1);
  asm volatile("s_waitcnt vmcnt(4)" ::: "memory");
  __builtin_amdgcn_s_barrier();

  for (int kt = 0; kt < nt; ++kt) {
    const int bu = kt % 3;
    if (kt + 2 < nt) STAGE3(kt + 2);

    s16x8 af[4], bf[4];
#pragma unroll
    for (int i = 0; i < 4; ++i) {
      int ra = wm * 64 + i * 16 + lr;
      af[i] = *(const s16x8*)&As[bu][ra * 32 + ((lk ^ ((ra >> 1) & 3)) << 3)];
      int rb = wn * 64 + i * 16 + lr;
      bf[i] = *(const s16x8*)&Bs[bu][rb * 32 + ((lk ^ ((rb >> 1) & 3)) << 3)];
    }
    __builtin_amdgcn_s_setprio(1);
#pragma unroll
    for (int i = 0; i < 4; ++i)
#pragma unroll
      for (int jn = 0; jn < 4; ++jn)
        acc[i][jn] = __builtin_amdgcn_mfma_f32_16x16x32_bf16(af[i], bf[jn], acc[i][jn], 0, 0, 0);
    __builtin_amdgcn_s_setprio(0);

    asm volatile("s_waitcnt lgkmcnt(0)" ::: "memory");
    if (kt + 2 < nt)       { asm volatile("s_waitcnt vmcnt(4)" ::: "memory"); }
    else if (kt + 2 == nt) { asm volatile("s_waitcnt vmcnt(0)" ::: "memory"); }
    if (kt + 1 < nt) __builtin_amdgcn_s_barrier();
  }
#undef STAGE3

#pragma unroll
  for (int i = 0; i < 4; ++i) {
    int row_b = m0 + wm * 64 + i * 16 + lk * 4;
#pragma unroll
    for (int jn = 0; jn < 4; ++jn) {
      int col = n0 + wn * 64 + jn * 16 + lr;
      float bv = BIAS ? bias[col] : 0.f;
#pragma unroll
      for (int r = 0; r < 4; ++r) {
        float v = acc[i][jn][r] + bv;
        size_t off = (size_t)(row_b + r) * N + col;
        if constexpr (sizeof(OutT) == 2) ((u16*)C)[off] = f2bf(v);
        else                             ((float*)C)[off] = v;
      }
    }
  }
}

// ---------------- Fused QKV GEMM, 8-phase 256x256xBK64 (T3+T4 structure) ----------------
// 8 waves (2M x 4N), per-wave 128x64 (m-interleaved frags), 2-dbuf 128KB LDS.
// Stage stream Delta=6 half-tiles ahead, per-tile order {Ah0,Bh1,Bh0,Ah1}:
// every stage-issue >=1 barrier-separated phase after the last read of its
// region. vmcnt(4) at each K-tile boundary (2 half-tiles stay in flight);
// vmcnt(0) only entering the last tile. 16 MFMA per phase between barriers.
__global__ __launch_bounds__(512) void gemm_qkv8(
    const u16* __restrict__ A, const u16* __restrict__ Bstk,
    u16* __restrict__ Qb, u16* __restrict__ Kb, u16* __restrict__ Vb)
{
  const int K = 4096;
  __shared__ u16 As[2][2][128 * 64];   // [buf][half][row*64+col]
  __shared__ u16 Bs[2][2][128 * 64];

  const int t = threadIdx.x;
  const int lane = t & 63, wid = t >> 6;
  const int wm = wid >> 2, wn = wid & 3;      // 2M x 4N
  const int lr = lane & 15, lk = lane >> 4;

  const int wg = blockIdx.x;                  // 0..383
  const int xcd = wg & 7, j = wg >> 3;        // j 0..47
  const int m0 = (j & 7) * 256;
  const int n0 = (xcd * 6 + (j >> 3)) * 256;  // 6 n-panels per XCD (B-panel 2MB, L2-fit)

  const int sr = t >> 3, sc = t & 7;          // staging: row/chunk decode

  f32x4 acc[8][4] = {};
  s16x8 af[4][2], bf[2][2];

  // stage one 16KB half: kind 0=Ah0 1=Bh1 2=Bh0 3=Ah1 of K-tile T
#define STAGE_K(kind, T)                                                       \
  {                                                                            \
    const int bu_ = (T) & 1, k0_ = (T) << 6;                                   \
    u16* slab_ = (kind) == 0 ? &As[bu_][0][0] : (kind) == 1 ? &Bs[bu_][1][0]   \
               : (kind) == 2 ? &Bs[bu_][0][0] : &As[bu_][1][0];                \
    const u16* src_ = ((kind) == 0 || (kind) == 3) ? A : Bstk;                 \
    const int rb_ = (kind) == 0 ? m0 : (kind) == 1 ? n0 + 128                  \
                  : (kind) == 2 ? n0 : m0 + 128;                               \
    _Pragma("unroll")                                                          \
    for (int it = 0; it < 2; ++it) {                                           \
      int r_ = it * 64 + sr;                                                   \
      gload_lds16(src_ + (size_t)(rb_ + r_) * K + k0_ + ((sc ^ (r_ & 7)) << 3),\
                  slab_ + (it * 512 + t) * 8);                                 \
    }                                                                          \
  }

#define RD_A(mh, bu)                                                           \
  _Pragma("unroll")                                                            \
  for (int f = 0; f < 4; ++f) {                                                \
    int rA = f * 32 + wm * 16 + lr;                                            \
    _Pragma("unroll")                                                          \
    for (int ks = 0; ks < 2; ++ks)                                             \
      af[f][ks] = *(const s16x8*)&As[bu][mh][rA * 64 +                         \
                    (((ks * 4 + lk) ^ (rA & 7)) << 3)];                        \
  }
#define RD_B(nh, bu)                                                           \
  _Pragma("unroll")                                                            \
  for (int e = 0; e < 2; ++e) {                                                \
    int rB = e * 64 + wn * 16 + lr;                                            \
    _Pragma("unroll")                                                          \
    for (int ks = 0; ks < 2; ++ks)                                             \
      bf[e][ks] = *(const s16x8*)&Bs[bu][nh][rB * 64 +                         \
                    (((ks * 4 + lk) ^ (rB & 7)) << 3)];                        \
  }
#define BAR_LGKM()                                                             \
  __builtin_amdgcn_s_barrier();                                                \
  asm volatile("s_waitcnt lgkmcnt(0)" ::: "memory");                           \
  __builtin_amdgcn_sched_barrier(0);
#define MM(mh, nh)                                                             \
  __builtin_amdgcn_s_setprio(1);                                               \
  _Pragma("unroll")                                                            \
  for (int f = 0; f < 4; ++f)                                                  \
    _Pragma("unroll")                                                          \
    for (int e = 0; e < 2; ++e)                                                \
      _Pragma("unroll")                                                        \
      for (int ks = 0; ks < 2; ++ks)                                           \
        acc[(mh) * 4 + f][(nh) * 2 + e] =                                      \
            __builtin_amdgcn_mfma_f32_16x16x32_bf16(                           \
                af[f][ks], bf[e][ks], acc[(mh) * 4 + f][(nh) * 2 + e], 0, 0, 0);\
  __builtin_amdgcn_s_setprio(0);

  const int NT = K >> 6;   // 64 K-tiles

  // prologue: halves 0..5 = tile0{Ah0,Bh1,Bh0,Ah1} + tile1{Ah0,Bh1}
  STAGE_K(0, 0); STAGE_K(1, 0); STAGE_K(2, 0); STAGE_K(3, 0);
  STAGE_K(0, 1); STAGE_K(1, 1);
  asm volatile("s_waitcnt vmcnt(4)" ::: "memory");   // tile 0 resident; 2 halves fly
  __builtin_amdgcn_s_barrier();

  for (int tau = 0; tau < NT; ++tau) {
    const int bu = tau & 1;

    // ph0: quadrant (mh0,nh0); stage Bh0(tau+1)
    RD_A(0, bu); RD_B(0, bu);
    if (tau + 1 < NT) STAGE_K(2, tau + 1);
    BAR_LGKM();
    MM(0, 0);
    __builtin_amdgcn_s_barrier();

    // ph1: (mh0,nh1); stage Ah1(tau+1)   [af reused]
    RD_B(1, bu);
    if (tau + 1 < NT) STAGE_K(3, tau + 1);
    BAR_LGKM();
    MM(0, 1);
    __builtin_amdgcn_s_barrier();

    // ph2: (mh1,nh1); stage Ah0(tau+2)   [bf reused; Ah0(tau) last read ph0]
    RD_A(1, bu);
    if (tau + 2 < NT) STAGE_K(0, tau + 2);
    BAR_LGKM();
    MM(1, 1);
    __builtin_amdgcn_s_barrier();

    // ph3: (mh1,nh0); stage Bh1(tau+2)   [Bh1(tau) last read ph2]
    RD_B(0, bu);
    if (tau + 2 < NT) STAGE_K(1, tau + 2);
    BAR_LGKM();
    MM(1, 0);
    // K-tile boundary: counted wait (2 halves of tau+2 may stay in flight)
    if (tau == NT - 2)     { asm volatile("s_waitcnt vmcnt(0)" ::: "memory"); }
    else if (tau < NT - 1) { asm volatile("s_waitcnt vmcnt(4)" ::: "memory"); }
    if (tau < NT - 1) __builtin_amdgcn_s_barrier();
  }
#undef STAGE_K
#undef RD_A
#undef RD_B
#undef BAR_LGKM
#undef MM

  // epilogue: route by n0; D layout col=lane&15, row=(lane>>4)*4+reg
  u16* Cp; int nb;
  if (n0 < 4096)      { Cp = Qb; nb = n0; }
  else if (n0 < 8192) { Cp = Kb; nb = n0 - 4096; }
  else                { Cp = Vb; nb = n0 - 8192; }

#pragma unroll
  for (int F = 0; F < 8; ++F) {
    int row_b = m0 + (F >> 2) * 128 + (F & 3) * 32 + wm * 16 + lk * 4;
#pragma unroll
    for (int E = 0; E < 4; ++E) {
      int col = nb + (E >> 1) * 128 + (E & 1) * 64 + wn * 16 + lr;
#pragma unroll
      for (int r = 0; r < 4; ++r)
        Cp[(size_t)(row_b + r) * 4096 + col] = f2bf(acc[F][E][r]);
    }
  }
}

// ---------------- Fused QKV GEMM (R13 fallback, 128^2) ----------------
__global__ __launch_bounds__(256) void gemm_qkv(
    const u16* __restrict__ A, const u16* __restrict__ Bstk,
    u16* __restrict__ Qb, u16* __restrict__ Kb, u16* __restrict__ Vb,
    int M, int K)
{
  __shared__ u16 As[3][128 * 32];
  __shared__ u16 Bs[3][128 * 32];

  const int t = threadIdx.x;
  const int lane = t & 63, wid = t >> 6;
  const int wm = wid >> 1, wn = wid & 1;
  const int lr = lane & 15, lk = lane >> 4;

  const int wg = blockIdx.x;
  const int xcd = wg & 7, j = wg >> 3;
  const int m0 = (j & 15) * 128;
  const int n0 = (xcd * 12 + (j >> 4)) * 128;

  const int nt = K >> 5;

  f32x4 acc[4][4] = {};

#define STAGEQ(KT)                                                             \
  {                                                                            \
    const int bu_ = (KT) % 3;                                                  \
    const int k0_ = (KT) << 5;                                                 \
    _Pragma("unroll")                                                          \
    for (int it = 0; it < 2; ++it) {                                           \
      int id = it * 256 + t;                                                   \
      int r = id >> 2, c0 = id & 3;                                            \
      int cs = (c0 ^ ((r >> 1) & 3)) << 3;                                     \
      gload_lds16(A + (size_t)(m0 + r) * K + k0_ + cs, &As[bu_][id * 8]);      \
      gload_lds16(Bstk + (size_t)(n0 + r) * K + k0_ + cs, &Bs[bu_][id * 8]);   \
    }                                                                          \
  }

  STAGEQ(0);
  STAGEQ(1);
  asm volatile("s_waitcnt vmcnt(4)" ::: "memory");
  __builtin_amdgcn_s_barrier();

  for (int kt = 0; kt < nt; ++kt) {
    const int bu = kt % 3;
    if (kt + 2 < nt) STAGEQ(kt + 2);

    s16x8 af[4], bf[4];
#pragma unroll
    for (int i = 0; i < 4; ++i) {
      int ra = wm * 64 + i * 16 + lr;
      af[i] = *(const s16x8*)&As[bu][ra * 32 + ((lk ^ ((ra >> 1) & 3)) << 3)];
      int rb = wn * 64 + i * 16 + lr;
      bf[i] = *(const s16x8*)&Bs[bu][rb * 32 + ((lk ^ ((rb >> 1) & 3)) << 3)];
    }
    __builtin_amdgcn_s_setprio(1);
#pragma unroll
    for (int i = 0; i < 4; ++i)
#pragma unroll
      for (int jn = 0; jn < 4; ++jn)
        acc[i][jn] = __builtin_amdgcn_mfma_f32_16x16x32_bf16(af[i], bf[jn], acc[i][jn], 0, 0, 0);
    __builtin_amdgcn_s_setprio(0);

    asm volatile("s_waitcnt lgkmcnt(0)" ::: "memory");
    if (kt + 2 < nt)       { asm volatile("s_waitcnt vmcnt(4)" ::: "memory"); }
    else if (kt + 2 == nt) { asm volatile("s_waitcnt vmcnt(0)" ::: "memory"); }
    if (kt + 1 < nt) __builtin_amdgcn_s_barrier();
  }
#undef STAGEQ

  u16* Cp; int nb;
  if (n0 < 4096)      { Cp = Qb; nb = n0; }
  else if (n0 < 8192) { Cp = Kb; nb = n0 - 4096; }
  else                { Cp = Vb; nb = n0 - 8192; }

#pragma unroll
  for (int i = 0; i < 4; ++i) {
    int row_b = m0 + wm * 64 + i * 16 + lk * 4;
#pragma unroll
    for (int jn = 0; jn < 4; ++jn) {
      int col = nb + wn * 64 + jn * 16 + lr;
#pragma unroll
      for (int r = 0; r < 4; ++r)
        Cp[(size_t)(row_b + r) * 4096 + col] = f2bf(acc[i][jn][r]);
    }
  }
}

// ---------------- RoPE on Q and K in place (bf16) ----------------
__global__ void rope_qk(u16* __restrict__ Q, u16* __restrict__ Kt,
                        const float* __restrict__ cosp, const float* __restrict__ sinp) {
  int i = blockIdx.x * 256 + threadIdx.x;   // over S*H*64
  int d = i & 63;
  int h = (i >> 6) & 31;
  int s = i >> 11;
  float c = cosp[s * 128 + d], sn = sinp[s * 128 + d];
  size_t base = (size_t)s * 4096 + h * 128 + d;
  float q1 = bf2f(Q[base]), q2 = bf2f(Q[base + 64]);
  Q[base]      = f2bf(q1 * c - q2 * sn);
  Q[base + 64] = f2bf(q2 * c + q1 * sn);
  float k1 = bf2f(Kt[base]), k2 = bf2f(Kt[base + 64]);
  Kt[base]      = f2bf(k1 * c - k2 * sn);
  Kt[base + 64] = f2bf(k2 * c + k1 * sn);
}

// ---------------- Flash attention v2 (R11 winner): QBLK=64, KVBLK=64, 4 waves ----------------
__global__ __launch_bounds__(256) void flash_attn(
    const u16* __restrict__ Q, const u16* __restrict__ Kg, const u16* __restrict__ Vg,
    u16* __restrict__ Ctx)
{
  const int D = 4096;
  __shared__ u16 Ks[2][64 * 128];
  __shared__ u16 Vt[128 * 64];

  const int t = threadIdx.x, lane = t & 63, wid = t >> 6;
  const int lr = lane & 15, lk = lane >> 4;

  const int wg = blockIdx.x;              // 0..1023
  const int xcd = wg & 7, j = wg >> 3;
  const int bx = 31 - (j >> 2);
  const int h = xcd * 4 + (j & 3);
  const int q0 = bx * 64;
  const int qw0 = q0 + wid * 16;

  s16x8 qf[4];
#pragma unroll
  for (int kc = 0; kc < 4; ++kc)
    qf[kc] = *(const s16x8*)(Q + (size_t)(qw0 + lr) * D + h * 128 + kc * 32 + lk * 8);

  f32x4 o[8] = {};
  float m_s = -1e30f, l_s = 0.f;

  const int ntiles = bx + 1;
  const float scale2 = 0.12751779f;

  const int ch = t & 15, kv4 = (t >> 4) * 4;

  {
#pragma unroll
    for (int it = 0; it < 4; ++it) {
      int id = it * 256 + t;
      int kv = id >> 4, c0 = id & 15;
      gload_lds16(Kg + (size_t)kv * D + h * 128 + ((c0 ^ (kv & 7)) << 3), &Ks[0][id * 8]);
    }
    const u16* src = Vg + (size_t)kv4 * D + h * 128 + ch * 8;
    s16x8 v0 = *(const s16x8*)src;
    s16x8 v1 = *(const s16x8*)(src + D);
    s16x8 v2 = *(const s16x8*)(src + 2 * D);
    s16x8 v3 = *(const s16x8*)(src + 3 * D);
#pragma unroll
    for (int jj = 0; jj < 8; ++jj) {
      int d = ch * 8 + jj;
      int sw = ((ch ^ jj) & 7) << 3;
      *(unsigned*)&Vt[d * 64 + ((kv4)     ^ sw)] = (unsigned)(u16)v0[jj] | ((unsigned)(u16)v1[jj] << 16);
      *(unsigned*)&Vt[d * 64 + ((kv4 + 2) ^ sw)] = (unsigned)(u16)v2[jj] | ((unsigned)(u16)v3[jj] << 16);
    }
  }

  for (int kt = 0; kt < ntiles; ++kt) {
    const int b = kt & 1;
    const int kv0 = kt * 64;
    __syncthreads();

    s16x8 v0, v1, v2, v3;
    const bool pf = (kt + 1 < ntiles);
    if (pf) {
      const u16* src = Vg + (size_t)(kv0 + 64 + kv4) * D + h * 128 + ch * 8;
      v0 = *(const s16x8*)src;
      v1 = *(const s16x8*)(src + D);
      v2 = *(const s16x8*)(src + 2 * D);
      v3 = *(const s16x8*)(src + 3 * D);
#pragma unroll
      for (int it = 0; it < 4; ++it) {
        int id = it * 256 + t;
        int kv = id >> 4, c0 = id & 15;
        gload_lds16(Kg + (size_t)(kv0 + 64 + kv) * D + h * 128 + ((c0 ^ (kv & 7)) << 3),
                    &Ks[b ^ 1][id * 8]);
      }
    }

    if (kv0 <= qw0 + 15) {
      const bool masked = (kv0 + 63 > qw0);

      f32x4 st[4] = {};
      __builtin_amdgcn_s_setprio(1);
#pragma unroll
      for (int nt = 0; nt < 4; ++nt) {
        int kv = nt * 16 + lr;
        int sw = kv & 7;
#pragma unroll
        for (int kc = 0; kc < 4; ++kc) {
          s16x8 kf = *(const s16x8*)&Ks[b][kv * 128 + (((4 * kc + lk) ^ sw) << 3)];
          st[nt] = __builtin_amdgcn_mfma_f32_16x16x32_bf16(kf, qf[kc], st[nt], 0, 0, 0);
        }
      }
      __builtin_amdgcn_s_setprio(0);

      float pm = -1e30f;
#pragma unroll
      for (int nt = 0; nt < 4; ++nt)
#pragma unroll
        for (int r = 0; r < 4; ++r) {
          float sv = st[nt][r] * scale2;
          if (masked && (kv0 + nt * 16 + lk * 4 + r > qw0 + lr)) sv = -1e30f;
          st[nt][r] = sv;
          pm = fmaxf(pm, sv);
        }
      pm = fmaxf(pm, __shfl_xor(pm, 16));
      pm = fmaxf(pm, __shfl_xor(pm, 32));

      if (__any(pm > m_s + 8.f)) {
        float mn = fmaxf(m_s, pm);
        float al = __builtin_amdgcn_exp2f(m_s - mn);
        m_s = mn; l_s *= al;
        float aq0 = __shfl(al, (lane & 48) | (lk * 4 + 0));
        float aq1 = __shfl(al, (lane & 48) | (lk * 4 + 1));
        float aq2 = __shfl(al, (lane & 48) | (lk * 4 + 2));
        float aq3 = __shfl(al, (lane & 48) | (lk * 4 + 3));
#pragma unroll
        for (int nb = 0; nb < 8; ++nb) {
          o[nb][0] *= aq0; o[nb][1] *= aq1; o[nb][2] *= aq2; o[nb][3] *= aq3;
        }
      }

      float ps = 0.f;
#pragma unroll
      for (int nt = 0; nt < 4; ++nt)
#pragma unroll
        for (int r = 0; r < 4; ++r) {
          float pv = __builtin_amdgcn_exp2f(st[nt][r] - m_s);
          st[nt][r] = pv;
          ps += pv;
        }
      ps += __shfl_xor(ps, 16);
      ps += __shfl_xor(ps, 32);
      l_s += ps;

      unsigned pkv[4][2];
#pragma unroll
      for (int nt = 0; nt < 4; ++nt) {
        pkv[nt][0] = pk2(st[nt][0], st[nt][1]);
        pkv[nt][1] = pk2(st[nt][2], st[nt][3]);
      }

      const int srcA = lr | (((lk & 1) * 2) << 4);
      const int srcB = srcA + 16;
      const bool sel = (lk >> 1) != 0;
      s16x8 pa[2];
#pragma unroll
      for (int ks = 0; ks < 2; ++ks) {
        int a0 = __shfl((int)pkv[ks * 2][0], srcA);
        int b0 = __shfl((int)pkv[ks * 2 + 1][0], srcA);
        int a1 = __shfl((int)pkv[ks * 2][1], srcA);
        int b1 = __shfl((int)pkv[ks * 2 + 1][1], srcA);
        int a2 = __shfl((int)pkv[ks * 2][0], srcB);
        int b2 = __shfl((int)pkv[ks * 2 + 1][0], srcB);
        int a3 = __shfl((int)pkv[ks * 2][1], srcB);
        int b3 = __shfl((int)pkv[ks * 2 + 1][1], srcB);
        int4 w = { sel ? b0 : a0, sel ? b1 : a1, sel ? b2 : a2, sel ? b3 : a3 };
        pa[ks] = *(s16x8*)&w;
      }

      __builtin_amdgcn_s_setprio(1);
#pragma unroll
      for (int ks = 0; ks < 2; ++ks) {
#pragma unroll
        for (int nb = 0; nb < 8; ++nb) {
          int d = nb * 16 + lr;
          int g = (((d >> 3) ^ d) & 7) << 3;
          s16x8 vf = *(const s16x8*)&Vt[d * 64 + ((ks * 32 + lk * 8) ^ g)];
          o[nb] = __builtin_amdgcn_mfma_f32_16x16x32_bf16(pa[ks], vf, o[nb], 0, 0, 0);
        }
      }
      __builtin_amdgcn_s_setprio(0);
    }

    if (pf) {
      __builtin_amdgcn_s_barrier();
#pragma unroll
      for (int jj = 0; jj < 8; ++jj) {
        int d = ch * 8 + jj;
        int sw = ((ch ^ jj) & 7) << 3;
        *(unsigned*)&Vt[d * 64 + ((kv4)     ^ sw)] = (unsigned)(u16)v0[jj] | ((unsigned)(u16)v1[jj] << 16);
        *(unsigned*)&Vt[d * 64 + ((kv4 + 2) ^ sw)] = (unsigned)(u16)v2[jj] | ((unsigned)(u16)v3[jj] << 16);
      }
    }
  }

  float linv = 1.f / l_s;
  float i0 = __shfl(linv, (lane & 48) | (lk * 4 + 0));
  float i1 = __shfl(linv, (lane & 48) | (lk * 4 + 1));
  float i2 = __shfl(linv, (lane & 48) | (lk * 4 + 2));
  float i3 = __shfl(linv, (lane & 48) | (lk * 4 + 3));
#pragma unroll
  for (int nb = 0; nb < 8; ++nb) {
    int d = h * 128 + nb * 16 + lr;
    Ctx[(size_t)(qw0 + lk * 4 + 0) * D + d] = f2bf(o[nb][0] * i0);
    Ctx[(size_t)(qw0 + lk * 4 + 1) * D + d] = f2bf(o[nb][1] * i1);
    Ctx[(size_t)(qw0 + lk * 4 + 2) * D + d] = f2bf(o[nb][2] * i2);
    Ctx[(size_t)(qw0 + lk * 4 + 3) * D + d] = f2bf(o[nb][3] * i3);
  }
}

// ---------------- launcher ----------------
extern "C" void kernel_launch(void* const* d_in, const int* in_sizes, int n_in,
                              void* d_out, int out_size, void* d_ws, size_t ws_size,
                              hipStream_t stream) {
  const int S = 2048, D = 4096, H = 32;
  const size_t SD = (size_t)S * D, DD = (size_t)D * D;

  const float* X  = (const float*)d_in[0];
  const float* Wq = (const float*)d_in[1];
  const float* Wk = (const float*)d_in[2];
  const float* Wv = (const float*)d_in[3];
  const float* Wo = (const float*)d_in[4];
  const float* bo = (const float*)d_in[5];
  const float* cs = (const float*)d_in[6];
  const float* sn = (const float*)d_in[7];

  dim3 blk(256);
  dim3 g3(512);
  dim3 b3(256);

  const size_t need_fused = (3 * DD + 4 * SD) * sizeof(u16);   // 160 MiB

  if (ws_size >= need_fused) {
    u16* WB3 = (u16*)d_ws;
    u16* Xb  = WB3 + 3 * DD;
    u16* Qb  = Xb + SD;
    u16* Kb  = Qb + SD;
    u16* Vb  = Kb + SD;

    cvt4<<<(int)((SD + 3 * DD) / 1024), blk, 0, stream>>>(X, Wq, Wk, Wv, Xb, WB3);

    gemm_qkv8<<<dim3(384), dim3(512), 0, stream>>>(Xb, WB3, Qb, Kb, Vb);

    rope_qk<<<(S * H * 64) / 256, blk, 0, stream>>>(Qb, Kb, cs, sn);
    flash_attn<<<dim3(1024), dim3(256), 0, stream>>>(Qb, Kb, Vb, Xb /*Ctx*/);

    cvt_f32_bf16<<<(int)(DD / 1024), blk, 0, stream>>>(Wo, WB3, (int)DD);
    gemm_bt3<float, true><<<g3, b3, 0, stream>>>(Xb, WB3, (float*)d_out, bo, S, D, D);
  } else {
    u16* WB = (u16*)d_ws;
    u16* Xb = WB + DD;
    u16* Qb = Xb + SD;
    u16* Kb = Qb + SD;
    u16* Vb = Kb + SD;

    cvt_f32_bf16<<<(int)(SD / 1024), blk, 0, stream>>>(X, Xb, (int)SD);
    cvt_f32_bf16<<<(int)(DD / 1024), blk, 0, stream>>>(Wq, WB, (int)DD);
    gemm_bt3<u16, false><<<g3, b3, 0, stream>>>(Xb, WB, Qb, nullptr, S, D, D);
    cvt_f32_bf16<<<(int)(DD / 1024), blk, 0, stream>>>(Wk, WB, (int)DD);
    gemm_bt3<u16, false><<<g3, b3, 0, stream>>>(Xb, WB, Kb, nullptr, S, D, D);
    cvt_f32_bf16<<<(int)(DD / 1024), blk, 0, stream>>>(Wv, WB, (int)DD);
    gemm_bt3<u16, false><<<g3, b3, 0, stream>>>(Xb, WB, Vb, nullptr, S, D, D);

    rope_qk<<<(S * H * 64) / 256, blk, 0, stream>>>(Qb, Kb, cs, sn);
    flash_attn<<<dim3(1024), dim3(256), 0, stream>>>(Qb, Kb, Vb, Xb /*Ctx*/);

    cvt_f32_bf16<<<(int)(DD / 1024), blk, 0, stream>>>(Wo, WB, (int)DD);
    gemm_bt3<float, true><<<g3, b3, 0, stream>>>(Xb, WB, (float*)d_out, bo, S, D, D);
  }
}

// Round 15
// 507.610 us; speedup vs baseline: 1.1210x; 1.1210x over previous
//
#include <hip/hip_runtime.h>

typedef unsigned short u16;
typedef __attribute__((ext_vector_type(8))) short s16x8;
typedef __attribute__((ext_vector_type(4))) float f32x4;

__device__ __forceinline__ u16 f2bf(float f) {
  unsigned u = __float_as_uint(f);
  u += 0x7fffu + ((u >> 16) & 1u);   // RNE
  return (u16)(u >> 16);
}
__device__ __forceinline__ float bf2f(u16 h) {
  return __uint_as_float(((unsigned)h) << 16);
}
__device__ __forceinline__ unsigned pk2(float lo, float hi) {
  return ((__float_as_uint(hi) + 0x8000u) & 0xffff0000u) |
         ((__float_as_uint(lo) + 0x8000u) >> 16);
}

typedef __attribute__((address_space(1))) const void gvoid_t;
typedef __attribute__((address_space(3))) void lvoid_t;
__device__ __forceinline__ void gload_lds16(const void* g, void* l) {
  __builtin_amdgcn_global_load_lds((gvoid_t*)g, (lvoid_t*)l, 16, 0, 0);
}

// ---------------- f32 -> bf16 convert (single region) ----------------
__global__ void cvt_f32_bf16(const float* __restrict__ in, u16* __restrict__ out, int n) {
  int i = (blockIdx.x * 256 + threadIdx.x) * 4;
  if (i >= n) return;
  float4 v = *(const float4*)(in + i);
  ushort4 o;
  o.x = f2bf(v.x); o.y = f2bf(v.y); o.z = f2bf(v.z); o.w = f2bf(v.w);
  *(ushort4*)(out + i) = o;
}

// ---------------- merged convert: X (2^23) + Wq/Wk/Wv (2^24 each) ----------------
__global__ void cvt4(const float* __restrict__ X,
                     const float* __restrict__ Wq, const float* __restrict__ Wk,
                     const float* __restrict__ Wv,
                     u16* __restrict__ Xb, u16* __restrict__ WB3) {
  long i = ((long)blockIdx.x * 256 + threadIdx.x) * 4;
  const float* src; u16* dst; long off;
  if (i < (1L << 23)) { src = X; dst = Xb; off = i; }
  else {
    long k = i - (1L << 23);
    int w = (int)(k >> 24);
    off = k & ((1L << 24) - 1);
    src = (w == 0) ? Wq : (w == 1) ? Wk : Wv;
    dst = WB3 + ((size_t)w << 24);
  }
  float4 v = *(const float4*)(src + off);
  ushort4 o;
  o.x = f2bf(v.x); o.y = f2bf(v.y); o.z = f2bf(v.z); o.w = f2bf(v.w);
  *(ushort4*)(dst + off) = o;
}

// ---------------- merged convert v2: X + Wq/Wk/Wv/Wo (needs 192 MiB ws) ----------------
__global__ void cvt5(const float* __restrict__ X,
                     const float* __restrict__ Wq, const float* __restrict__ Wk,
                     const float* __restrict__ Wv, const float* __restrict__ Wo,
                     u16* __restrict__ Xb, u16* __restrict__ WB4) {
  long i = ((long)blockIdx.x * 256 + threadIdx.x) * 4;
  const float* src; u16* dst; long off;
  if (i < (1L << 23)) { src = X; dst = Xb; off = i; }
  else {
    long k = i - (1L << 23);
    int w = (int)(k >> 24);                    // 0..3
    off = k & ((1L << 24) - 1);
    src = (w == 0) ? Wq : (w == 1) ? Wk : (w == 2) ? Wv : Wo;
    dst = WB4 + ((size_t)w << 24);
  }
  float4 v = *(const float4*)(src + off);
  ushort4 o;
  o.x = f2bf(v.x); o.y = f2bf(v.y); o.z = f2bf(v.z); o.w = f2bf(v.w);
  *(ushort4*)(dst + off) = o;
}

// ---------------- GEMM (R13 winner): out-proj ----------------
template<typename OutT, bool BIAS>
__global__ __launch_bounds__(256) void gemm_bt3(
    const u16* __restrict__ A, const u16* __restrict__ Bm,
    OutT* __restrict__ C, const float* __restrict__ bias,
    int M, int N, int K)
{
  __shared__ u16 As[3][128 * 32];
  __shared__ u16 Bs[3][128 * 32];

  const int t = threadIdx.x;
  const int lane = t & 63, wid = t >> 6;
  const int wm = wid >> 1, wn = wid & 1;
  const int lr = lane & 15, lk = lane >> 4;

  const int wg = blockIdx.x;
  const int xcd = wg & 7, j = wg >> 3;
  const int m0 = (j & 15) * 128;
  const int n0 = ((xcd << 2) | (j >> 4)) * 128;

  const int nt = K >> 5;

  f32x4 acc[4][4] = {};

#define STAGE3(KT)                                                             \
  {                                                                            \
    const int bu_ = (KT) % 3;                                                  \
    const int k0_ = (KT) << 5;                                                 \
    _Pragma("unroll")                                                          \
    for (int it = 0; it < 2; ++it) {                                           \
      int id = it * 256 + t;                                                   \
      int r = id >> 2, c0 = id & 3;                                            \
      int cs = (c0 ^ ((r >> 1) & 3)) << 3;                                     \
      gload_lds16(A + (size_t)(m0 + r) * K + k0_ + cs, &As[bu_][id * 8]);      \
      gload_lds16(Bm + (size_t)(n0 + r) * K + k0_ + cs, &Bs[bu_][id * 8]);     \
    }                                                                          \
  }

  STAGE3(0);
  STAGE3(1);
  asm volatile("s_waitcnt vmcnt(4)" ::: "memory");
  __builtin_amdgcn_s_barrier();

  for (int kt = 0; kt < nt; ++kt) {
    const int bu = kt % 3;
    if (kt + 2 < nt) STAGE3(kt + 2);

    s16x8 af[4], bf[4];
#pragma unroll
    for (int i = 0; i < 4; ++i) {
      int ra = wm * 64 + i * 16 + lr;
      af[i] = *(const s16x8*)&As[bu][ra * 32 + ((lk ^ ((ra >> 1) & 3)) << 3)];
      int rb = wn * 64 + i * 16 + lr;
      bf[i] = *(const s16x8*)&Bs[bu][rb * 32 + ((lk ^ ((rb >> 1) & 3)) << 3)];
    }
    __builtin_amdgcn_s_setprio(1);
#pragma unroll
    for (int i = 0; i < 4; ++i)
#pragma unroll
      for (int jn = 0; jn < 4; ++jn)
        acc[i][jn] = __builtin_amdgcn_mfma_f32_16x16x32_bf16(af[i], bf[jn], acc[i][jn], 0, 0, 0);
    __builtin_amdgcn_s_setprio(0);

    asm volatile("s_waitcnt lgkmcnt(0)" ::: "memory");
    if (kt + 2 < nt)       { asm volatile("s_waitcnt vmcnt(4)" ::: "memory"); }
    else if (kt + 2 == nt) { asm volatile("s_waitcnt vmcnt(0)" ::: "memory"); }
    if (kt + 1 < nt) __builtin_amdgcn_s_barrier();
  }
#undef STAGE3

#pragma unroll
  for (int i = 0; i < 4; ++i) {
    int row_b = m0 + wm * 64 + i * 16 + lk * 4;
#pragma unroll
    for (int jn = 0; jn < 4; ++jn) {
      int col = n0 + wn * 64 + jn * 16 + lr;
      float bv = BIAS ? bias[col] : 0.f;
#pragma unroll
      for (int r = 0; r < 4; ++r) {
        float v = acc[i][jn][r] + bv;
        size_t off = (size_t)(row_b + r) * N + col;
        if constexpr (sizeof(OutT) == 2) ((u16*)C)[off] = f2bf(v);
        else                             ((float*)C)[off] = v;
      }
    }
  }
}

// ---------------- Fused QKV GEMM (R13 winner, 128^2 2-phase) ----------------
__global__ __launch_bounds__(256) void gemm_qkv(
    const u16* __restrict__ A, const u16* __restrict__ Bstk,
    u16* __restrict__ Qb, u16* __restrict__ Kb, u16* __restrict__ Vb,
    int M, int K)
{
  __shared__ u16 As[3][128 * 32];
  __shared__ u16 Bs[3][128 * 32];

  const int t = threadIdx.x;
  const int lane = t & 63, wid = t >> 6;
  const int wm = wid >> 1, wn = wid & 1;
  const int lr = lane & 15, lk = lane >> 4;

  const int wg = blockIdx.x;
  const int xcd = wg & 7, j = wg >> 3;
  const int m0 = (j & 15) * 128;
  const int n0 = (xcd * 12 + (j >> 4)) * 128;

  const int nt = K >> 5;

  f32x4 acc[4][4] = {};

#define STAGEQ(KT)                                                             \
  {                                                                            \
    const int bu_ = (KT) % 3;                                                  \
    const int k0_ = (KT) << 5;                                                 \
    _Pragma("unroll")                                                          \
    for (int it = 0; it < 2; ++it) {                                           \
      int id = it * 256 + t;                                                   \
      int r = id >> 2, c0 = id & 3;                                            \
      int cs = (c0 ^ ((r >> 1) & 3)) << 3;                                     \
      gload_lds16(A + (size_t)(m0 + r) * K + k0_ + cs, &As[bu_][id * 8]);      \
      gload_lds16(Bstk + (size_t)(n0 + r) * K + k0_ + cs, &Bs[bu_][id * 8]);   \
    }                                                                          \
  }

  STAGEQ(0);
  STAGEQ(1);
  asm volatile("s_waitcnt vmcnt(4)" ::: "memory");
  __builtin_amdgcn_s_barrier();

  for (int kt = 0; kt < nt; ++kt) {
    const int bu = kt % 3;
    if (kt + 2 < nt) STAGEQ(kt + 2);

    s16x8 af[4], bf[4];
#pragma unroll
    for (int i = 0; i < 4; ++i) {
      int ra = wm * 64 + i * 16 + lr;
      af[i] = *(const s16x8*)&As[bu][ra * 32 + ((lk ^ ((ra >> 1) & 3)) << 3)];
      int rb = wn * 64 + i * 16 + lr;
      bf[i] = *(const s16x8*)&Bs[bu][rb * 32 + ((lk ^ ((rb >> 1) & 3)) << 3)];
    }
    __builtin_amdgcn_s_setprio(1);
#pragma unroll
    for (int i = 0; i < 4; ++i)
#pragma unroll
      for (int jn = 0; jn < 4; ++jn)
        acc[i][jn] = __builtin_amdgcn_mfma_f32_16x16x32_bf16(af[i], bf[jn], acc[i][jn], 0, 0, 0);
    __builtin_amdgcn_s_setprio(0);

    asm volatile("s_waitcnt lgkmcnt(0)" ::: "memory");
    if (kt + 2 < nt)       { asm volatile("s_waitcnt vmcnt(4)" ::: "memory"); }
    else if (kt + 2 == nt) { asm volatile("s_waitcnt vmcnt(0)" ::: "memory"); }
    if (kt + 1 < nt) __builtin_amdgcn_s_barrier();
  }
#undef STAGEQ

  u16* Cp; int nb;
  if (n0 < 4096)      { Cp = Qb; nb = n0; }
  else if (n0 < 8192) { Cp = Kb; nb = n0 - 4096; }
  else                { Cp = Vb; nb = n0 - 8192; }

#pragma unroll
  for (int i = 0; i < 4; ++i) {
    int row_b = m0 + wm * 64 + i * 16 + lk * 4;
#pragma unroll
    for (int jn = 0; jn < 4; ++jn) {
      int col = nb + wn * 64 + jn * 16 + lr;
#pragma unroll
      for (int r = 0; r < 4; ++r)
        Cp[(size_t)(row_b + r) * 4096 + col] = f2bf(acc[i][jn][r]);
    }
  }
}

// ---------------- RoPE on Q and K in place (bf16) ----------------
__global__ void rope_qk(u16* __restrict__ Q, u16* __restrict__ Kt,
                        const float* __restrict__ cosp, const float* __restrict__ sinp) {
  int i = blockIdx.x * 256 + threadIdx.x;   // over S*H*64
  int d = i & 63;
  int h = (i >> 6) & 31;
  int s = i >> 11;
  float c = cosp[s * 128 + d], sn = sinp[s * 128 + d];
  size_t base = (size_t)s * 4096 + h * 128 + d;
  float q1 = bf2f(Q[base]), q2 = bf2f(Q[base + 64]);
  Q[base]      = f2bf(q1 * c - q2 * sn);
  Q[base + 64] = f2bf(q2 * c + q1 * sn);
  float k1 = bf2f(Kt[base]), k2 = bf2f(Kt[base + 64]);
  Kt[base]      = f2bf(k1 * c - k2 * sn);
  Kt[base + 64] = f2bf(k2 * c + k1 * sn);
}

// ---------------- Flash attention v2 (R11 winner): QBLK=64, KVBLK=64, 4 waves ----------------
__global__ __launch_bounds__(256) void flash_attn(
    const u16* __restrict__ Q, const u16* __restrict__ Kg, const u16* __restrict__ Vg,
    u16* __restrict__ Ctx)
{
  const int D = 4096;
  __shared__ u16 Ks[2][64 * 128];
  __shared__ u16 Vt[128 * 64];

  const int t = threadIdx.x, lane = t & 63, wid = t >> 6;
  const int lr = lane & 15, lk = lane >> 4;

  const int wg = blockIdx.x;              // 0..1023
  const int xcd = wg & 7, j = wg >> 3;
  const int bx = 31 - (j >> 2);
  const int h = xcd * 4 + (j & 3);
  const int q0 = bx * 64;
  const int qw0 = q0 + wid * 16;

  s16x8 qf[4];
#pragma unroll
  for (int kc = 0; kc < 4; ++kc)
    qf[kc] = *(const s16x8*)(Q + (size_t)(qw0 + lr) * D + h * 128 + kc * 32 + lk * 8);

  f32x4 o[8] = {};
  float m_s = -1e30f, l_s = 0.f;

  const int ntiles = bx + 1;
  const float scale2 = 0.12751779f;

  const int ch = t & 15, kv4 = (t >> 4) * 4;

  {
#pragma unroll
    for (int it = 0; it < 4; ++it) {
      int id = it * 256 + t;
      int kv = id >> 4, c0 = id & 15;
      gload_lds16(Kg + (size_t)kv * D + h * 128 + ((c0 ^ (kv & 7)) << 3), &Ks[0][id * 8]);
    }
    const u16* src = Vg + (size_t)kv4 * D + h * 128 + ch * 8;
    s16x8 v0 = *(const s16x8*)src;
    s16x8 v1 = *(const s16x8*)(src + D);
    s16x8 v2 = *(const s16x8*)(src + 2 * D);
    s16x8 v3 = *(const s16x8*)(src + 3 * D);
#pragma unroll
    for (int jj = 0; jj < 8; ++jj) {
      int d = ch * 8 + jj;
      int sw = ((ch ^ jj) & 7) << 3;
      *(unsigned*)&Vt[d * 64 + ((kv4)     ^ sw)] = (unsigned)(u16)v0[jj] | ((unsigned)(u16)v1[jj] << 16);
      *(unsigned*)&Vt[d * 64 + ((kv4 + 2) ^ sw)] = (unsigned)(u16)v2[jj] | ((unsigned)(u16)v3[jj] << 16);
    }
  }

  for (int kt = 0; kt < ntiles; ++kt) {
    const int b = kt & 1;
    const int kv0 = kt * 64;
    __syncthreads();

    s16x8 v0, v1, v2, v3;
    const bool pf = (kt + 1 < ntiles);
    if (pf) {
      const u16* src = Vg + (size_t)(kv0 + 64 + kv4) * D + h * 128 + ch * 8;
      v0 = *(const s16x8*)src;
      v1 = *(const s16x8*)(src + D);
      v2 = *(const s16x8*)(src + 2 * D);
      v3 = *(const s16x8*)(src + 3 * D);
#pragma unroll
      for (int it = 0; it < 4; ++it) {
        int id = it * 256 + t;
        int kv = id >> 4, c0 = id & 15;
        gload_lds16(Kg + (size_t)(kv0 + 64 + kv) * D + h * 128 + ((c0 ^ (kv & 7)) << 3),
                    &Ks[b ^ 1][id * 8]);
      }
    }

    if (kv0 <= qw0 + 15) {
      const bool masked = (kv0 + 63 > qw0);

      f32x4 st[4] = {};
      __builtin_amdgcn_s_setprio(1);
#pragma unroll
      for (int nt = 0; nt < 4; ++nt) {
        int kv = nt * 16 + lr;
        int sw = kv & 7;
#pragma unroll
        for (int kc = 0; kc < 4; ++kc) {
          s16x8 kf = *(const s16x8*)&Ks[b][kv * 128 + (((4 * kc + lk) ^ sw) << 3)];
          st[nt] = __builtin_amdgcn_mfma_f32_16x16x32_bf16(kf, qf[kc], st[nt], 0, 0, 0);
        }
      }
      __builtin_amdgcn_s_setprio(0);

      float pm = -1e30f;
#pragma unroll
      for (int nt = 0; nt < 4; ++nt)
#pragma unroll
        for (int r = 0; r < 4; ++r) {
          float sv = st[nt][r] * scale2;
          if (masked && (kv0 + nt * 16 + lk * 4 + r > qw0 + lr)) sv = -1e30f;
          st[nt][r] = sv;
          pm = fmaxf(pm, sv);
        }
      pm = fmaxf(pm, __shfl_xor(pm, 16));
      pm = fmaxf(pm, __shfl_xor(pm, 32));

      if (__any(pm > m_s + 8.f)) {
        float mn = fmaxf(m_s, pm);
        float al = __builtin_amdgcn_exp2f(m_s - mn);
        m_s = mn; l_s *= al;
        float aq0 = __shfl(al, (lane & 48) | (lk * 4 + 0));
        float aq1 = __shfl(al, (lane & 48) | (lk * 4 + 1));
        float aq2 = __shfl(al, (lane & 48) | (lk * 4 + 2));
        float aq3 = __shfl(al, (lane & 48) | (lk * 4 + 3));
#pragma unroll
        for (int nb = 0; nb < 8; ++nb) {
          o[nb][0] *= aq0; o[nb][1] *= aq1; o[nb][2] *= aq2; o[nb][3] *= aq3;
        }
      }

      float ps = 0.f;
#pragma unroll
      for (int nt = 0; nt < 4; ++nt)
#pragma unroll
        for (int r = 0; r < 4; ++r) {
          float pv = __builtin_amdgcn_exp2f(st[nt][r] - m_s);
          st[nt][r] = pv;
          ps += pv;
        }
      ps += __shfl_xor(ps, 16);
      ps += __shfl_xor(ps, 32);
      l_s += ps;

      unsigned pkv[4][2];
#pragma unroll
      for (int nt = 0; nt < 4; ++nt) {
        pkv[nt][0] = pk2(st[nt][0], st[nt][1]);
        pkv[nt][1] = pk2(st[nt][2], st[nt][3]);
      }

      const int srcA = lr | (((lk & 1) * 2) << 4);
      const int srcB = srcA + 16;
      const bool sel = (lk >> 1) != 0;
      s16x8 pa[2];
#pragma unroll
      for (int ks = 0; ks < 2; ++ks) {
        int a0 = __shfl((int)pkv[ks * 2][0], srcA);
        int b0 = __shfl((int)pkv[ks * 2 + 1][0], srcA);
        int a1 = __shfl((int)pkv[ks * 2][1], srcA);
        int b1 = __shfl((int)pkv[ks * 2 + 1][1], srcA);
        int a2 = __shfl((int)pkv[ks * 2][0], srcB);
        int b2 = __shfl((int)pkv[ks * 2 + 1][0], srcB);
        int a3 = __shfl((int)pkv[ks * 2][1], srcB);
        int b3 = __shfl((int)pkv[ks * 2 + 1][1], srcB);
        int4 w = { sel ? b0 : a0, sel ? b1 : a1, sel ? b2 : a2, sel ? b3 : a3 };
        pa[ks] = *(s16x8*)&w;
      }

      __builtin_amdgcn_s_setprio(1);
#pragma unroll
      for (int ks = 0; ks < 2; ++ks) {
#pragma unroll
        for (int nb = 0; nb < 8; ++nb) {
          int d = nb * 16 + lr;
          int g = (((d >> 3) ^ d) & 7) << 3;
          s16x8 vf = *(const s16x8*)&Vt[d * 64 + ((ks * 32 + lk * 8) ^ g)];
          o[nb] = __builtin_amdgcn_mfma_f32_16x16x32_bf16(pa[ks], vf, o[nb], 0, 0, 0);
        }
      }
      __builtin_amdgcn_s_setprio(0);
    }

    if (pf) {
      __builtin_amdgcn_s_barrier();
#pragma unroll
      for (int jj = 0; jj < 8; ++jj) {
        int d = ch * 8 + jj;
        int sw = ((ch ^ jj) & 7) << 3;
        *(unsigned*)&Vt[d * 64 + ((kv4)     ^ sw)] = (unsigned)(u16)v0[jj] | ((unsigned)(u16)v1[jj] << 16);
        *(unsigned*)&Vt[d * 64 + ((kv4 + 2) ^ sw)] = (unsigned)(u16)v2[jj] | ((unsigned)(u16)v3[jj] << 16);
      }
    }
  }

  float linv = 1.f / l_s;
  float i0 = __shfl(linv, (lane & 48) | (lk * 4 + 0));
  float i1 = __shfl(linv, (lane & 48) | (lk * 4 + 1));
  float i2 = __shfl(linv, (lane & 48) | (lk * 4 + 2));
  float i3 = __shfl(linv, (lane & 48) | (lk * 4 + 3));
#pragma unroll
  for (int nb = 0; nb < 8; ++nb) {
    int d = h * 128 + nb * 16 + lr;
    Ctx[(size_t)(qw0 + lk * 4 + 0) * D + d] = f2bf(o[nb][0] * i0);
    Ctx[(size_t)(qw0 + lk * 4 + 1) * D + d] = f2bf(o[nb][1] * i1);
    Ctx[(size_t)(qw0 + lk * 4 + 2) * D + d] = f2bf(o[nb][2] * i2);
    Ctx[(size_t)(qw0 + lk * 4 + 3) * D + d] = f2bf(o[nb][3] * i3);
  }
}

// ---------------- launcher ----------------
extern "C" void kernel_launch(void* const* d_in, const int* in_sizes, int n_in,
                              void* d_out, int out_size, void* d_ws, size_t ws_size,
                              hipStream_t stream) {
  const int S = 2048, D = 4096, H = 32;
  const size_t SD = (size_t)S * D, DD = (size_t)D * D;

  const float* X  = (const float*)d_in[0];
  const float* Wq = (const float*)d_in[1];
  const float* Wk = (const float*)d_in[2];
  const float* Wv = (const float*)d_in[3];
  const float* Wo = (const float*)d_in[4];
  const float* bo = (const float*)d_in[5];
  const float* cs = (const float*)d_in[6];
  const float* sn = (const float*)d_in[7];

  dim3 blk(256);
  dim3 g3(512);
  dim3 b3(256);

  const size_t need5 = (4 * DD + 4 * SD) * sizeof(u16);   // 192 MiB
  const size_t need4 = (3 * DD + 4 * SD) * sizeof(u16);   // 160 MiB

  if (ws_size >= need5) {
    // all-merged convert: WB4 = [Wq;Wk;Wv;Wo]
    u16* WB4 = (u16*)d_ws;
    u16* Xb  = WB4 + 4 * DD;
    u16* Qb  = Xb + SD;
    u16* Kb  = Qb + SD;
    u16* Vb  = Kb + SD;

    cvt5<<<(int)((SD + 4 * DD) / 1024), blk, 0, stream>>>(X, Wq, Wk, Wv, Wo, Xb, WB4);

    gemm_qkv<<<dim3(1536), b3, 0, stream>>>(Xb, WB4, Qb, Kb, Vb, S, D);

    rope_qk<<<(S * H * 64) / 256, blk, 0, stream>>>(Qb, Kb, cs, sn);
    flash_attn<<<dim3(1024), dim3(256), 0, stream>>>(Qb, Kb, Vb, Xb /*Ctx*/);

    gemm_bt3<float, true><<<g3, b3, 0, stream>>>(Xb, WB4 + 3 * DD, (float*)d_out, bo, S, D, D);
  } else if (ws_size >= need4) {
    // R13 path
    u16* WB3 = (u16*)d_ws;
    u16* Xb  = WB3 + 3 * DD;
    u16* Qb  = Xb + SD;
    u16* Kb  = Qb + SD;
    u16* Vb  = Kb + SD;

    cvt4<<<(int)((SD + 3 * DD) / 1024), blk, 0, stream>>>(X, Wq, Wk, Wv, Xb, WB3);

    gemm_qkv<<<dim3(1536), b3, 0, stream>>>(Xb, WB3, Qb, Kb, Vb, S, D);

    rope_qk<<<(S * H * 64) / 256, blk, 0, stream>>>(Qb, Kb, cs, sn);
    flash_attn<<<dim3(1024), dim3(256), 0, stream>>>(Qb, Kb, Vb, Xb /*Ctx*/);

    cvt_f32_bf16<<<(int)(DD / 1024), blk, 0, stream>>>(Wo, WB3, (int)DD);
    gemm_bt3<float, true><<<g3, b3, 0, stream>>>(Xb, WB3, (float*)d_out, bo, S, D, D);
  } else {
    // serial fallback (96 MiB): reuse one weight slab via per-GEMM converts
    u16* WB = (u16*)d_ws;
    u16* Xb = WB + DD;
    u16* Qb = Xb + SD;
    u16* Kb = Qb + SD;
    u16* Vb = Kb + SD;

    cvt_f32_bf16<<<(int)(SD / 1024), blk, 0, stream>>>(X, Xb, (int)SD);
    cvt_f32_bf16<<<(int)(DD / 1024), blk, 0, stream>>>(Wq, WB, (int)DD);
    gemm_bt3<u16, false><<<g3, b3, 0, stream>>>(Xb, WB, Qb, nullptr, S, D, D);
    cvt_f32_bf16<<<(int)(DD / 1024), blk, 0, stream>>>(Wk, WB, (int)DD);
    gemm_bt3<u16, false><<<g3, b3, 0, stream>>>(Xb, WB, Kb, nullptr, S, D, D);
    cvt_f32_bf16<<<(int)(DD / 1024), blk, 0, stream>>>(Wv, WB, (int)DD);
    gemm_bt3<u16, false><<<g3, b3, 0, stream>>>(Xb, WB, Vb, nullptr, S, D, D);

    rope_qk<<<(S * H * 64) / 256, blk, 0, stream>>>(Qb, Kb, cs, sn);
    flash_attn<<<dim3(1024), dim3(256), 0, stream>>>(Qb, Kb, Vb, Xb /*Ctx*/);

    cvt_f32_bf16<<<(int)(DD / 1024), blk, 0, stream>>>(Wo, WB, (int)DD);
    gemm_bt3<float, true><<<g3, b3, 0, stream>>>(Xb, WB, (float*)d_out, bo, S, D, D);
  }
}

// Round 16
// 483.325 us; speedup vs baseline: 1.1773x; 1.0502x over previous
//
#include <hip/hip_runtime.h>

typedef unsigned short u16;
typedef __attribute__((ext_vector_type(8))) short s16x8;
typedef __attribute__((ext_vector_type(4))) float f32x4;

__device__ __forceinline__ u16 f2bf(float f) {
  unsigned u = __float_as_uint(f);
  u += 0x7fffu + ((u >> 16) & 1u);   // RNE
  return (u16)(u >> 16);
}
__device__ __forceinline__ float bf2f(u16 h) {
  return __uint_as_float(((unsigned)h) << 16);
}
// round-half-up f32->bf16 pair pack (P values; <=1ulp vs RNE)
__device__ __forceinline__ unsigned pk2(float lo, float hi) {
  return ((__float_as_uint(hi) + 0x8000u) & 0xffff0000u) |
         ((__float_as_uint(lo) + 0x8000u) >> 16);
}

typedef __attribute__((address_space(1))) const void gvoid_t;
typedef __attribute__((address_space(3))) void lvoid_t;
__device__ __forceinline__ void gload_lds16(const void* g, void* l) {
  __builtin_amdgcn_global_load_lds((gvoid_t*)g, (lvoid_t*)l, 16, 0, 0);
}

// ---------------- f32 -> bf16 convert (single region) ----------------
__global__ void cvt_f32_bf16(const float* __restrict__ in, u16* __restrict__ out, int n) {
  int i = (blockIdx.x * 256 + threadIdx.x) * 4;
  if (i >= n) return;
  float4 v = *(const float4*)(in + i);
  ushort4 o;
  o.x = f2bf(v.x); o.y = f2bf(v.y); o.z = f2bf(v.z); o.w = f2bf(v.w);
  *(ushort4*)(out + i) = o;
}

// ---------------- merged convert: X (2^23) + Wq/Wk/Wv (2^24 each) ----------------
__global__ void cvt4(const float* __restrict__ X,
                     const float* __restrict__ Wq, const float* __restrict__ Wk,
                     const float* __restrict__ Wv,
                     u16* __restrict__ Xb, u16* __restrict__ WB3) {
  long i = ((long)blockIdx.x * 256 + threadIdx.x) * 4;
  const float* src; u16* dst; long off;
  if (i < (1L << 23)) { src = X; dst = Xb; off = i; }
  else {
    long k = i - (1L << 23);
    int w = (int)(k >> 24);
    off = k & ((1L << 24) - 1);
    src = (w == 0) ? Wq : (w == 1) ? Wk : Wv;
    dst = WB3 + ((size_t)w << 24);
  }
  float4 v = *(const float4*)(src + off);
  ushort4 o;
  o.x = f2bf(v.x); o.y = f2bf(v.y); o.z = f2bf(v.z); o.w = f2bf(v.w);
  *(ushort4*)(dst + off) = o;
}

// ---------------- GEMM (16x16x32): C[M,N] = A[M,K]*B[N,K]^T ----------------
// 128x128 tile, BK=32, 256 thr (4 waves 2x2), 3-buffered 48KB LDS, counted
// vmcnt(4), one barrier per K-tile. Fragment reads conflict-free (measured 0).
template<typename OutT, bool BIAS>
__global__ __launch_bounds__(256) void gemm_bt3(
    const u16* __restrict__ A, const u16* __restrict__ Bm,
    OutT* __restrict__ C, const float* __restrict__ bias,
    int M, int N, int K)
{
  __shared__ u16 As[3][128 * 32];
  __shared__ u16 Bs[3][128 * 32];

  const int t = threadIdx.x;
  const int lane = t & 63, wid = t >> 6;
  const int wm = wid >> 1, wn = wid & 1;
  const int lr = lane & 15, lk = lane >> 4;

  const int wg = blockIdx.x;
  const int xcd = wg & 7, j = wg >> 3;           // j 0..63
  const int m0 = (j & 15) * 128;
  const int n0 = ((xcd << 2) | (j >> 4)) * 128;

  const int nt = K >> 5;

  f32x4 acc[4][4] = {};

#define STAGE3(KT)                                                             \
  {                                                                            \
    const int bu_ = (KT) % 3;                                                  \
    const int k0_ = (KT) << 5;                                                 \
    _Pragma("unroll")                                                          \
    for (int it = 0; it < 2; ++it) {                                           \
      int id = it * 256 + t;                                                   \
      int r = id >> 2, c0 = id & 3;                                            \
      int cs = (c0 ^ ((r >> 1) & 3)) << 3;                                     \
      gload_lds16(A + (size_t)(m0 + r) * K + k0_ + cs, &As[bu_][id * 8]);      \
      gload_lds16(Bm + (size_t)(n0 + r) * K + k0_ + cs, &Bs[bu_][id * 8]);     \
    }                                                                          \
  }

  STAGE3(0);
  STAGE3(1);
  asm volatile("s_waitcnt vmcnt(4)" ::: "memory");
  __builtin_amdgcn_s_barrier();

  for (int kt = 0; kt < nt; ++kt) {
    const int bu = kt % 3;
    if (kt + 2 < nt) STAGE3(kt + 2);

    s16x8 af[4], bf[4];
#pragma unroll
    for (int i = 0; i < 4; ++i) {
      int ra = wm * 64 + i * 16 + lr;
      af[i] = *(const s16x8*)&As[bu][ra * 32 + ((lk ^ ((ra >> 1) & 3)) << 3)];
      int rb = wn * 64 + i * 16 + lr;
      bf[i] = *(const s16x8*)&Bs[bu][rb * 32 + ((lk ^ ((rb >> 1) & 3)) << 3)];
    }
    __builtin_amdgcn_s_setprio(1);
#pragma unroll
    for (int i = 0; i < 4; ++i)
#pragma unroll
      for (int jn = 0; jn < 4; ++jn)
        acc[i][jn] = __builtin_amdgcn_mfma_f32_16x16x32_bf16(af[i], bf[jn], acc[i][jn], 0, 0, 0);
    __builtin_amdgcn_s_setprio(0);

    asm volatile("s_waitcnt lgkmcnt(0)" ::: "memory");
    if (kt + 2 < nt)       { asm volatile("s_waitcnt vmcnt(4)" ::: "memory"); }
    else if (kt + 2 == nt) { asm volatile("s_waitcnt vmcnt(0)" ::: "memory"); }
    if (kt + 1 < nt) __builtin_amdgcn_s_barrier();
  }
#undef STAGE3

#pragma unroll
  for (int i = 0; i < 4; ++i) {
    int row_b = m0 + wm * 64 + i * 16 + lk * 4;
#pragma unroll
    for (int jn = 0; jn < 4; ++jn) {
      int col = n0 + wn * 64 + jn * 16 + lr;
      float bv = BIAS ? bias[col] : 0.f;
#pragma unroll
      for (int r = 0; r < 4; ++r) {
        float v = acc[i][jn][r] + bv;
        size_t off = (size_t)(row_b + r) * N + col;
        if constexpr (sizeof(OutT) == 2) ((u16*)C)[off] = f2bf(v);
        else                             ((float*)C)[off] = v;
      }
    }
  }
}

// ---------------- Fused QKV GEMM (16x16x32) ----------------
__global__ __launch_bounds__(256) void gemm_qkv(
    const u16* __restrict__ A, const u16* __restrict__ Bstk,
    u16* __restrict__ Qb, u16* __restrict__ Kb, u16* __restrict__ Vb,
    int M, int K)
{
  __shared__ u16 As[3][128 * 32];
  __shared__ u16 Bs[3][128 * 32];

  const int t = threadIdx.x;
  const int lane = t & 63, wid = t >> 6;
  const int wm = wid >> 1, wn = wid & 1;
  const int lr = lane & 15, lk = lane >> 4;

  const int wg = blockIdx.x;
  const int xcd = wg & 7, j = wg >> 3;            // j 0..191
  const int m0 = (j & 15) * 128;
  const int n0 = (xcd * 12 + (j >> 4)) * 128;     // 0..12160

  const int nt = K >> 5;

  f32x4 acc[4][4] = {};

#define STAGEQ(KT)                                                             \
  {                                                                            \
    const int bu_ = (KT) % 3;                                                  \
    const int k0_ = (KT) << 5;                                                 \
    _Pragma("unroll")                                                          \
    for (int it = 0; it < 2; ++it) {                                           \
      int id = it * 256 + t;                                                   \
      int r = id >> 2, c0 = id & 3;                                            \
      int cs = (c0 ^ ((r >> 1) & 3)) << 3;                                     \
      gload_lds16(A + (size_t)(m0 + r) * K + k0_ + cs, &As[bu_][id * 8]);      \
      gload_lds16(Bstk + (size_t)(n0 + r) * K + k0_ + cs, &Bs[bu_][id * 8]);   \
    }                                                                          \
  }

  STAGEQ(0);
  STAGEQ(1);
  asm volatile("s_waitcnt vmcnt(4)" ::: "memory");
  __builtin_amdgcn_s_barrier();

  for (int kt = 0; kt < nt; ++kt) {
    const int bu = kt % 3;
    if (kt + 2 < nt) STAGEQ(kt + 2);

    s16x8 af[4], bf[4];
#pragma unroll
    for (int i = 0; i < 4; ++i) {
      int ra = wm * 64 + i * 16 + lr;
      af[i] = *(const s16x8*)&As[bu][ra * 32 + ((lk ^ ((ra >> 1) & 3)) << 3)];
      int rb = wn * 64 + i * 16 + lr;
      bf[i] = *(const s16x8*)&Bs[bu][rb * 32 + ((lk ^ ((rb >> 1) & 3)) << 3)];
    }
    __builtin_amdgcn_s_setprio(1);
#pragma unroll
    for (int i = 0; i < 4; ++i)
#pragma unroll
      for (int jn = 0; jn < 4; ++jn)
        acc[i][jn] = __builtin_amdgcn_mfma_f32_16x16x32_bf16(af[i], bf[jn], acc[i][jn], 0, 0, 0);
    __builtin_amdgcn_s_setprio(0);

    asm volatile("s_waitcnt lgkmcnt(0)" ::: "memory");
    if (kt + 2 < nt)       { asm volatile("s_waitcnt vmcnt(4)" ::: "memory"); }
    else if (kt + 2 == nt) { asm volatile("s_waitcnt vmcnt(0)" ::: "memory"); }
    if (kt + 1 < nt) __builtin_amdgcn_s_barrier();
  }
#undef STAGEQ

  u16* Cp; int nb;
  if (n0 < 4096)      { Cp = Qb; nb = n0; }
  else if (n0 < 8192) { Cp = Kb; nb = n0 - 4096; }
  else                { Cp = Vb; nb = n0 - 8192; }

#pragma unroll
  for (int i = 0; i < 4; ++i) {
    int row_b = m0 + wm * 64 + i * 16 + lk * 4;
#pragma unroll
    for (int jn = 0; jn < 4; ++jn) {
      int col = nb + wn * 64 + jn * 16 + lr;
#pragma unroll
      for (int r = 0; r < 4; ++r)
        Cp[(size_t)(row_b + r) * 4096 + col] = f2bf(acc[i][jn][r]);
    }
  }
}

// ---------------- RoPE on Q and K in place (bf16) ----------------
__global__ void rope_qk(u16* __restrict__ Q, u16* __restrict__ Kt,
                        const float* __restrict__ cosp, const float* __restrict__ sinp) {
  int i = blockIdx.x * 256 + threadIdx.x;   // over S*H*64
  int d = i & 63;
  int h = (i >> 6) & 31;
  int s = i >> 11;
  float c = cosp[s * 128 + d], sn = sinp[s * 128 + d];
  size_t base = (size_t)s * 4096 + h * 128 + d;
  float q1 = bf2f(Q[base]), q2 = bf2f(Q[base + 64]);
  Q[base]      = f2bf(q1 * c - q2 * sn);
  Q[base + 64] = f2bf(q2 * c + q1 * sn);
  float k1 = bf2f(Kt[base]), k2 = bf2f(Kt[base + 64]);
  Kt[base]      = f2bf(k1 * c - k2 * sn);
  Kt[base + 64] = f2bf(k2 * c + k1 * sn);
}

// ---------------- Flash attention v2: QBLK=64, KVBLK=64, 4 waves, 48KB LDS ----------------
__global__ __launch_bounds__(256) void flash_attn(
    const u16* __restrict__ Q, const u16* __restrict__ Kg, const u16* __restrict__ Vg,
    u16* __restrict__ Ctx)
{
  const int D = 4096;
  __shared__ u16 Ks[2][64 * 128];
  __shared__ u16 Vt[128 * 64];

  const int t = threadIdx.x, lane = t & 63, wid = t >> 6;
  const int lr = lane & 15, lk = lane >> 4;

  const int wg = blockIdx.x;              // 0..1023
  const int xcd = wg & 7, j = wg >> 3;
  const int bx = 31 - (j >> 2);
  const int h = xcd * 4 + (j & 3);
  const int q0 = bx * 64;
  const int qw0 = q0 + wid * 16;

  s16x8 qf[4];
#pragma unroll
  for (int kc = 0; kc < 4; ++kc)
    qf[kc] = *(const s16x8*)(Q + (size_t)(qw0 + lr) * D + h * 128 + kc * 32 + lk * 8);

  f32x4 o[8] = {};
  float m_s = -1e30f, l_s = 0.f;

  const int ntiles = bx + 1;
  const float scale2 = 0.12751779f;

  const int ch = t & 15, kv4 = (t >> 4) * 4;

  {
#pragma unroll
    for (int it = 0; it < 4; ++it) {
      int id = it * 256 + t;
      int kv = id >> 4, c0 = id & 15;
      gload_lds16(Kg + (size_t)kv * D + h * 128 + ((c0 ^ (kv & 7)) << 3), &Ks[0][id * 8]);
    }
    const u16* src = Vg + (size_t)kv4 * D + h * 128 + ch * 8;
    s16x8 v0 = *(const s16x8*)src;
    s16x8 v1 = *(const s16x8*)(src + D);
    s16x8 v2 = *(const s16x8*)(src + 2 * D);
    s16x8 v3 = *(const s16x8*)(src + 3 * D);
#pragma unroll
    for (int jj = 0; jj < 8; ++jj) {
      int d = ch * 8 + jj;
      int sw = ((ch ^ jj) & 7) << 3;
      *(unsigned*)&Vt[d * 64 + ((kv4)     ^ sw)] = (unsigned)(u16)v0[jj] | ((unsigned)(u16)v1[jj] << 16);
      *(unsigned*)&Vt[d * 64 + ((kv4 + 2) ^ sw)] = (unsigned)(u16)v2[jj] | ((unsigned)(u16)v3[jj] << 16);
    }
  }

  for (int kt = 0; kt < ntiles; ++kt) {
    const int b = kt & 1;
    const int kv0 = kt * 64;
    __syncthreads();

    s16x8 v0, v1, v2, v3;
    const bool pf = (kt + 1 < ntiles);
    if (pf) {
      const u16* src = Vg + (size_t)(kv0 + 64 + kv4) * D + h * 128 + ch * 8;
      v0 = *(const s16x8*)src;
      v1 = *(const s16x8*)(src + D);
      v2 = *(const s16x8*)(src + 2 * D);
      v3 = *(const s16x8*)(src + 3 * D);
#pragma unroll
      for (int it = 0; it < 4; ++it) {
        int id = it * 256 + t;
        int kv = id >> 4, c0 = id & 15;
        gload_lds16(Kg + (size_t)(kv0 + 64 + kv) * D + h * 128 + ((c0 ^ (kv & 7)) << 3),
                    &Ks[b ^ 1][id * 8]);
      }
    }

    if (kv0 <= qw0 + 15) {
      const bool masked = (kv0 + 63 > qw0);

      f32x4 st[4] = {};
      __builtin_amdgcn_s_setprio(1);
#pragma unroll
      for (int nt = 0; nt < 4; ++nt) {
        int kv = nt * 16 + lr;
        int sw = kv & 7;
#pragma unroll
        for (int kc = 0; kc < 4; ++kc) {
          s16x8 kf = *(const s16x8*)&Ks[b][kv * 128 + (((4 * kc + lk) ^ sw) << 3)];
          st[nt] = __builtin_amdgcn_mfma_f32_16x16x32_bf16(kf, qf[kc], st[nt], 0, 0, 0);
        }
      }
      __builtin_amdgcn_s_setprio(0);

      float pm = -1e30f;
#pragma unroll
      for (int nt = 0; nt < 4; ++nt)
#pragma unroll
        for (int r = 0; r < 4; ++r) {
          float sv = st[nt][r] * scale2;
          if (masked && (kv0 + nt * 16 + lk * 4 + r > qw0 + lr)) sv = -1e30f;
          st[nt][r] = sv;
          pm = fmaxf(pm, sv);
        }
      pm = fmaxf(pm, __shfl_xor(pm, 16));
      pm = fmaxf(pm, __shfl_xor(pm, 32));

      if (__any(pm > m_s + 8.f)) {
        float mn = fmaxf(m_s, pm);
        float al = __builtin_amdgcn_exp2f(m_s - mn);
        m_s = mn; l_s *= al;
        float aq0 = __shfl(al, (lane & 48) | (lk * 4 + 0));
        float aq1 = __shfl(al, (lane & 48) | (lk * 4 + 1));
        float aq2 = __shfl(al, (lane & 48) | (lk * 4 + 2));
        float aq3 = __shfl(al, (lane & 48) | (lk * 4 + 3));
#pragma unroll
        for (int nb = 0; nb < 8; ++nb) {
          o[nb][0] *= aq0; o[nb][1] *= aq1; o[nb][2] *= aq2; o[nb][3] *= aq3;
        }
      }

      float ps = 0.f;
#pragma unroll
      for (int nt = 0; nt < 4; ++nt)
#pragma unroll
        for (int r = 0; r < 4; ++r) {
          float pv = __builtin_amdgcn_exp2f(st[nt][r] - m_s);
          st[nt][r] = pv;
          ps += pv;
        }
      ps += __shfl_xor(ps, 16);
      ps += __shfl_xor(ps, 32);
      l_s += ps;

      unsigned pkv[4][2];
#pragma unroll
      for (int nt = 0; nt < 4; ++nt) {
        pkv[nt][0] = pk2(st[nt][0], st[nt][1]);
        pkv[nt][1] = pk2(st[nt][2], st[nt][3]);
      }

      const int srcA = lr | (((lk & 1) * 2) << 4);
      const int srcB = srcA + 16;
      const bool sel = (lk >> 1) != 0;
      s16x8 pa[2];
#pragma unroll
      for (int ks = 0; ks < 2; ++ks) {
        int a0 = __shfl((int)pkv[ks * 2][0], srcA);
        int b0 = __shfl((int)pkv[ks * 2 + 1][0], srcA);
        int a1 = __shfl((int)pkv[ks * 2][1], srcA);
        int b1 = __shfl((int)pkv[ks * 2 + 1][1], srcA);
        int a2 = __shfl((int)pkv[ks * 2][0], srcB);
        int b2 = __shfl((int)pkv[ks * 2 + 1][0], srcB);
        int a3 = __shfl((int)pkv[ks * 2][1], srcB);
        int b3 = __shfl((int)pkv[ks * 2 + 1][1], srcB);
        int4 w = { sel ? b0 : a0, sel ? b1 : a1, sel ? b2 : a2, sel ? b3 : a3 };
        pa[ks] = *(s16x8*)&w;
      }

      __builtin_amdgcn_s_setprio(1);
#pragma unroll
      for (int ks = 0; ks < 2; ++ks) {
#pragma unroll
        for (int nb = 0; nb < 8; ++nb) {
          int d = nb * 16 + lr;
          int g = (((d >> 3) ^ d) & 7) << 3;
          s16x8 vf = *(const s16x8*)&Vt[d * 64 + ((ks * 32 + lk * 8) ^ g)];
          o[nb] = __builtin_amdgcn_mfma_f32_16x16x32_bf16(pa[ks], vf, o[nb], 0, 0, 0);
        }
      }
      __builtin_amdgcn_s_setprio(0);
    }

    if (pf) {
      __builtin_amdgcn_s_barrier();
#pragma unroll
      for (int jj = 0; jj < 8; ++jj) {
        int d = ch * 8 + jj;
        int sw = ((ch ^ jj) & 7) << 3;
        *(unsigned*)&Vt[d * 64 + ((kv4)     ^ sw)] = (unsigned)(u16)v0[jj] | ((unsigned)(u16)v1[jj] << 16);
        *(unsigned*)&Vt[d * 64 + ((kv4 + 2) ^ sw)] = (unsigned)(u16)v2[jj] | ((unsigned)(u16)v3[jj] << 16);
      }
    }
  }

  float linv = 1.f / l_s;
  float i0 = __shfl(linv, (lane & 48) | (lk * 4 + 0));
  float i1 = __shfl(linv, (lane & 48) | (lk * 4 + 1));
  float i2 = __shfl(linv, (lane & 48) | (lk * 4 + 2));
  float i3 = __shfl(linv, (lane & 48) | (lk * 4 + 3));
#pragma unroll
  for (int nb = 0; nb < 8; ++nb) {
    int d = h * 128 + nb * 16 + lr;
    Ctx[(size_t)(qw0 + lk * 4 + 0) * D + d] = f2bf(o[nb][0] * i0);
    Ctx[(size_t)(qw0 + lk * 4 + 1) * D + d] = f2bf(o[nb][1] * i1);
    Ctx[(size_t)(qw0 + lk * 4 + 2) * D + d] = f2bf(o[nb][2] * i2);
    Ctx[(size_t)(qw0 + lk * 4 + 3) * D + d] = f2bf(o[nb][3] * i3);
  }
}

// ---------------- launcher ----------------
extern "C" void kernel_launch(void* const* d_in, const int* in_sizes, int n_in,
                              void* d_out, int out_size, void* d_ws, size_t ws_size,
                              hipStream_t stream) {
  const int S = 2048, D = 4096, H = 32;
  const size_t SD = (size_t)S * D, DD = (size_t)D * D;

  const float* X  = (const float*)d_in[0];
  const float* Wq = (const float*)d_in[1];
  const float* Wk = (const float*)d_in[2];
  const float* Wv = (const float*)d_in[3];
  const float* Wo = (const float*)d_in[4];
  const float* bo = (const float*)d_in[5];
  const float* cs = (const float*)d_in[6];
  const float* sn = (const float*)d_in[7];

  dim3 blk(256);
  dim3 g3(512);
  dim3 b3(256);

  const size_t need_fused = (3 * DD + 4 * SD) * sizeof(u16);   // 160 MiB

  if (ws_size >= need_fused) {
    u16* WB3 = (u16*)d_ws;
    u16* Xb  = WB3 + 3 * DD;
    u16* Qb  = Xb + SD;
    u16* Kb  = Qb + SD;
    u16* Vb  = Kb + SD;

    cvt4<<<(int)((SD + 3 * DD) / 1024), blk, 0, stream>>>(X, Wq, Wk, Wv, Xb, WB3);

    gemm_qkv<<<dim3(1536), b3, 0, stream>>>(Xb, WB3, Qb, Kb, Vb, S, D);

    rope_qk<<<(S * H * 64) / 256, blk, 0, stream>>>(Qb, Kb, cs, sn);
    flash_attn<<<dim3(1024), dim3(256), 0, stream>>>(Qb, Kb, Vb, Xb /*Ctx*/);

    cvt_f32_bf16<<<(int)(DD / 1024), blk, 0, stream>>>(Wo, WB3, (int)DD);
    gemm_bt3<float, true><<<g3, b3, 0, stream>>>(Xb, WB3, (float*)d_out, bo, S, D, D);
  } else {
    u16* WB = (u16*)d_ws;
    u16* Xb = WB + DD;
    u16* Qb = Xb + SD;
    u16* Kb = Qb + SD;
    u16* Vb = Kb + SD;

    cvt_f32_bf16<<<(int)(SD / 1024), blk, 0, stream>>>(X, Xb, (int)SD);
    cvt_f32_bf16<<<(int)(DD / 1024), blk, 0, stream>>>(Wq, WB, (int)DD);
    gemm_bt3<u16, false><<<g3, b3, 0, stream>>>(Xb, WB, Qb, nullptr, S, D, D);
    cvt_f32_bf16<<<(int)(DD / 1024), blk, 0, stream>>>(Wk, WB, (int)DD);
    gemm_bt3<u16, false><<<g3, b3, 0, stream>>>(Xb, WB, Kb, nullptr, S, D, D);
    cvt_f32_bf16<<<(int)(DD / 1024), blk, 0, stream>>>(Wv, WB, (int)DD);
    gemm_bt3<u16, false><<<g3, b3, 0, stream>>>(Xb, WB, Vb, nullptr, S, D, D);

    rope_qk<<<(S * H * 64) / 256, blk, 0, stream>>>(Qb, Kb, cs, sn);
    flash_attn<<<dim3(1024), dim3(256), 0, stream>>>(Qb, Kb, Vb, Xb /*Ctx*/);

    cvt_f32_bf16<<<(int)(DD / 1024), blk, 0, stream>>>(Wo, WB, (int)DD);
    gemm_bt3<float, true><<<g3, b3, 0, stream>>>(Xb, WB, (float*)d_out, bo, S, D, D);
  }
}